// Round 1
// baseline (193.764 us; speedup 1.0000x reference)
//
#include <hip/hip_runtime.h>
#include <hip/hip_bf16.h>

#define NUM_ENT 50000
#define NUM_REL 500
#define DIM 128
#define BQ 1024
#define KN 32
#define TBL 729          // dt in [-364, 364]
#define NPAD 50048       // 782*64

typedef _Float16 f16x8 __attribute__((ext_vector_type(8)));
typedef _Float16 f16x4 __attribute__((ext_vector_type(4)));
typedef float f32x4 __attribute__((ext_vector_type(4)));

// ---------------- Kernel A: fold weights ----------------
// W[j][d], j<256:  sum_f gcn_w_w[d,f] * proj_w[f,j]        (node part j<128, cos part j>=128)
// W[256+f'][d]:    gcn_w_w[d,128+f']                        (relation half, transposed)
// bias[d] = sum_f proj_b[f]*gcn_w_w[d,f] + gcn_w_b[d]
// Call[d] = sum_g cos(phase[g])*proj_w[d,128+g] + proj_b[d]
__global__ void prep_weights(const float* __restrict__ gcn_w_w,
                             const float* __restrict__ gcn_w_b,
                             const float* __restrict__ proj_w,
                             const float* __restrict__ proj_b,
                             const float* __restrict__ phase,
                             float* __restrict__ W,
                             float* __restrict__ bias,
                             float* __restrict__ Call) {
    int j = blockIdx.x;
    int d = threadIdx.x;
    if (j < 256) {
        float acc = 0.f;
        for (int f = 0; f < DIM; ++f)
            acc += gcn_w_w[d * 256 + f] * proj_w[f * 256 + j];
        W[j * DIM + d] = acc;
    } else if (j < 384) {
        W[j * DIM + d] = gcn_w_w[d * 256 + 128 + (j - 256)];
    } else {
        float b1 = 0.f;
        for (int f = 0; f < DIM; ++f) b1 += proj_b[f] * gcn_w_w[d * 256 + f];
        bias[d] = b1 + gcn_w_b[d];
        float cc = 0.f;
        for (int g = 0; g < DIM; ++g) cc += cosf(phase[g]) * proj_w[d * 256 + 128 + g];
        Call[d] = cc + proj_b[d];
    }
}

// ---------------- Kernel B: cos table ----------------
__global__ void prep_cos(const float* __restrict__ basis_freq,
                         const float* __restrict__ phase,
                         float* __restrict__ COS) {
    int idx = blockIdx.x * 256 + threadIdx.x;
    if (idx >= TBL * DIM) return;
    int dt = idx / DIM - 364;
    int d  = idx % DIM;
    COS[idx] = cosf((float)dt * basis_freq[d] + phase[d]);
}

// ---------------- Kernel S: symbol_emb -> f16 (padded rows zeroed) -------------
__global__ void conv_f16(const float* __restrict__ S, _Float16* __restrict__ Sf) {
    int idx = blockIdx.x * 256 + threadIdx.x;       // one quad per thread
    if (idx >= NPAD * (DIM / 4)) return;
    int base = idx * 4;
    int row = base >> 7;
    float4 v;
    if (row < NUM_ENT) v = *reinterpret_cast<const float4*>(S + base);
    else               v = make_float4(0.f, 0.f, 0.f, 0.f);
    f16x4 o;
    o[0] = (_Float16)v.x; o[1] = (_Float16)v.y;
    o[2] = (_Float16)v.z; o[3] = (_Float16)v.w;
    *reinterpret_cast<f16x4*>(Sf + base) = o;
}

// ---------------- Kernel C: per-query pipeline ----------------
// aggregate gathers -> out_sum -> tanh -> q -> u = q@P1 (f16), c = q.Call (f32)
__global__ void query_kernel(const int* __restrict__ rel_idx,
                             const int* __restrict__ ts,
                             const int* __restrict__ ngh_node,
                             const int* __restrict__ ngh_eidx,
                             const int* __restrict__ ngh_ts,
                             const float* __restrict__ symbol_emb,
                             const float* __restrict__ proj_w,
                             const float* __restrict__ W,
                             const float* __restrict__ bias,
                             const float* __restrict__ Call,
                             const float* __restrict__ COS,
                             float* __restrict__ cOut,
                             _Float16* __restrict__ uOut) {
    int b = blockIdx.x;
    int t = threadIdx.x;   // 0..127
    __shared__ int sE[KN], sR[KN], sT[KN];
    __shared__ float sAgg[3][DIM];
    __shared__ float sQ[DIM];
    __shared__ float sRed[DIM];

    if (t < KN) {
        sE[t] = ngh_node[b * KN + t];
        sR[t] = ngh_eidx[b * KN + t];
        sT[t] = ngh_ts[b * KN + t] - ts[b] + 364;
    }
    __syncthreads();

    float aN = 0.f, aC = 0.f, aR = 0.f;
    int cnt = 0;
    for (int k = 0; k < KN; ++k) {
        int e = sE[k];
        if (e < 0) continue;
        cnt++;
        aN += symbol_emb[e * DIM + t];
        aC += COS[sT[k] * DIM + t];
        aR += symbol_emb[(NUM_ENT + sR[k]) * DIM + t];
    }
    sAgg[0][t] = aN; sAgg[1][t] = aC; sAgg[2][t] = aR;
    __syncthreads();

    float acc = (float)cnt * bias[t];
    #pragma unroll 8
    for (int j = 0; j < DIM; ++j) acc += sAgg[0][j] * W[j * DIM + t];
    #pragma unroll 8
    for (int j = 0; j < DIM; ++j) acc += sAgg[1][j] * W[(128 + j) * DIM + t];
    #pragma unroll 8
    for (int j = 0; j < DIM; ++j) acc += sAgg[2][j] * W[(256 + j) * DIM + t];

    float denom = (float)(cnt > 0 ? cnt : 1);
    float sub = tanhf(acc / denom);
    float q = sub * symbol_emb[(NUM_ENT + rel_idx[b]) * DIM + t];
    sQ[t] = q;
    __syncthreads();

    float u = 0.f;
    #pragma unroll 8
    for (int dd = 0; dd < DIM; ++dd) u += sQ[dd] * proj_w[dd * 256 + t];
    uOut[b * DIM + t] = (_Float16)u;

    sRed[t] = q * Call[t];
    __syncthreads();
    for (int s = 64; s > 0; s >>= 1) {
        if (t < s) sRed[t] += sRed[t + s];
        __syncthreads();
    }
    if (t == 0) cOut[b] = sRed[0];
}

// ---------------- Kernel D: score = U @ Sf^T + c ----------------
// M=1024 (b), N=50000 (e), K=128. Block: 4 waves, 64x64 tile; wave = 16x64.
__global__ __launch_bounds__(256) void score_kernel(const _Float16* __restrict__ U,
                                                    const _Float16* __restrict__ Sf,
                                                    const float* __restrict__ cArr,
                                                    float* __restrict__ out) {
    int lane = threadIdx.x & 63;
    int wave = threadIdx.x >> 6;
    int m0 = blockIdx.y * 64 + wave * 16;
    int n0 = blockIdx.x * 64;
    int lr = lane & 15;          // A row / B col within 16
    int lk = (lane >> 4) * 8;    // k offset within 32

    f32x4 acc[4];
    #pragma unroll
    for (int n = 0; n < 4; ++n) acc[n] = (f32x4){0.f, 0.f, 0.f, 0.f};

    f16x8 a[4];
    const _Float16* up = U + (m0 + lr) * DIM + lk;
    #pragma unroll
    for (int kk = 0; kk < 4; ++kk)
        a[kk] = *reinterpret_cast<const f16x8*>(up + kk * 32);

    #pragma unroll
    for (int kk = 0; kk < 4; ++kk) {
        #pragma unroll
        for (int n = 0; n < 4; ++n) {
            f16x8 bf = *reinterpret_cast<const f16x8*>(
                Sf + (n0 + n * 16 + lr) * DIM + kk * 32 + lk);
            acc[n] = __builtin_amdgcn_mfma_f32_16x16x32_f16(a[kk], bf, acc[n], 0, 0, 0);
        }
    }

    int rbase = m0 + ((lane >> 4) << 2);
    float cv[4];
    #pragma unroll
    for (int r = 0; r < 4; ++r) cv[r] = cArr[rbase + r];

    #pragma unroll
    for (int n = 0; n < 4; ++n) {
        int col = n0 + n * 16 + lr;
        if (col < NUM_ENT) {
            #pragma unroll
            for (int r = 0; r < 4; ++r)
                out[(size_t)(rbase + r) * NUM_ENT + col] = acc[n][r] + cv[r];
        }
    }
}

extern "C" void kernel_launch(void* const* d_in, const int* in_sizes, int n_in,
                              void* d_out, int out_size, void* d_ws, size_t ws_size,
                              hipStream_t stream) {
    const int*   rel_idx    = (const int*)d_in[1];
    const int*   ts         = (const int*)d_in[2];
    const int*   ngh_node   = (const int*)d_in[3];
    const int*   ngh_eidx   = (const int*)d_in[4];
    const int*   ngh_ts     = (const int*)d_in[5];
    const float* symbol_emb = (const float*)d_in[6];
    const float* gcn_w_w    = (const float*)d_in[7];
    const float* gcn_w_b    = (const float*)d_in[8];
    const float* proj_w     = (const float*)d_in[9];
    const float* proj_b     = (const float*)d_in[10];
    const float* basis_freq = (const float*)d_in[11];
    const float* phase      = (const float*)d_in[12];
    float* out = (float*)d_out;

    char* ws = (char*)d_ws;
    float*     W    = (float*)(ws + 0);          // 384*128*4 = 196608
    float*     bias = (float*)(ws + 196608);     // 512
    float*     Call = (float*)(ws + 197120);     // 512
    float*     COS  = (float*)(ws + 197632);     // 729*128*4 = 373248
    float*     cArr = (float*)(ws + 570880);     // 1024*4 = 4096
    _Float16*  U    = (_Float16*)(ws + 574976);  // 1024*128*2 = 262144
    _Float16*  Sf   = (_Float16*)(ws + 837120);  // 50048*128*2 = 12812288

    prep_weights<<<385, 128, 0, stream>>>(gcn_w_w, gcn_w_b, proj_w, proj_b, phase,
                                          W, bias, Call);
    prep_cos<<<(TBL * DIM + 255) / 256, 256, 0, stream>>>(basis_freq, phase, COS);
    conv_f16<<<NPAD * (DIM / 4) / 256, 256, 0, stream>>>(symbol_emb, Sf);
    query_kernel<<<BQ, 128, 0, stream>>>(rel_idx, ts, ngh_node, ngh_eidx, ngh_ts,
                                         symbol_emb, proj_w, W, bias, Call, COS,
                                         cArr, U);
    score_kernel<<<dim3(NPAD / 64, BQ / 64), 256, 0, stream>>>(U, Sf, cArr, out);
}

// Round 2
// 134.506 us; speedup vs baseline: 1.4406x; 1.4406x over previous
//
#include <hip/hip_runtime.h>
#include <hip/hip_bf16.h>

#define NUM_ENT 50000
#define NUM_REL 500
#define DIM 128
#define BQ 1024
#define KN 32
#define TBL 729          // dt in [-364, 364]
#define NPAD 50048       // 782*64

typedef _Float16 f16x8 __attribute__((ext_vector_type(8)));
typedef _Float16 f16x4 __attribute__((ext_vector_type(4)));
typedef float f32x4 __attribute__((ext_vector_type(4)));

// ---------------- Kernel A: fold weights ----------------
__global__ void prep_weights(const float* __restrict__ gcn_w_w,
                             const float* __restrict__ gcn_w_b,
                             const float* __restrict__ proj_w,
                             const float* __restrict__ proj_b,
                             const float* __restrict__ phase,
                             float* __restrict__ W,
                             float* __restrict__ bias,
                             float* __restrict__ Call) {
    int j = blockIdx.x;
    int d = threadIdx.x;
    if (j < 256) {
        float acc = 0.f;
        for (int f = 0; f < DIM; ++f)
            acc += gcn_w_w[d * 256 + f] * proj_w[f * 256 + j];
        W[j * DIM + d] = acc;
    } else if (j < 384) {
        W[j * DIM + d] = gcn_w_w[d * 256 + 128 + (j - 256)];
    } else {
        float b1 = 0.f;
        for (int f = 0; f < DIM; ++f) b1 += proj_b[f] * gcn_w_w[d * 256 + f];
        bias[d] = b1 + gcn_w_b[d];
        float cc = 0.f;
        for (int g = 0; g < DIM; ++g) cc += cosf(phase[g]) * proj_w[d * 256 + 128 + g];
        Call[d] = cc + proj_b[d];
    }
}

// ---------------- Kernel B: cos table ----------------
__global__ void prep_cos(const float* __restrict__ basis_freq,
                         const float* __restrict__ phase,
                         float* __restrict__ COS) {
    int idx = blockIdx.x * 256 + threadIdx.x;
    if (idx >= TBL * DIM) return;
    int dt = idx / DIM - 364;
    int d  = idx % DIM;
    COS[idx] = cosf((float)dt * basis_freq[d] + phase[d]);
}

// ---------------- Kernel S: symbol_emb -> f16 (padded rows zeroed) -------------
__global__ void conv_f16(const float* __restrict__ S, _Float16* __restrict__ Sf) {
    int idx = blockIdx.x * 256 + threadIdx.x;       // one quad per thread
    if (idx >= NPAD * (DIM / 4)) return;
    int base = idx * 4;
    int row = base >> 7;
    float4 v;
    if (row < NUM_ENT) v = *reinterpret_cast<const float4*>(S + base);
    else               v = make_float4(0.f, 0.f, 0.f, 0.f);
    f16x4 o;
    o[0] = (_Float16)v.x; o[1] = (_Float16)v.y;
    o[2] = (_Float16)v.z; o[3] = (_Float16)v.w;
    *reinterpret_cast<f16x4*>(Sf + base) = o;
}

// ---------------- Kernel C: per-query pipeline ----------------
__global__ void query_kernel(const int* __restrict__ rel_idx,
                             const int* __restrict__ ts,
                             const int* __restrict__ ngh_node,
                             const int* __restrict__ ngh_eidx,
                             const int* __restrict__ ngh_ts,
                             const float* __restrict__ symbol_emb,
                             const float* __restrict__ proj_w,
                             const float* __restrict__ W,
                             const float* __restrict__ bias,
                             const float* __restrict__ Call,
                             const float* __restrict__ COS,
                             float* __restrict__ cOut,
                             _Float16* __restrict__ uOut) {
    int b = blockIdx.x;
    int t = threadIdx.x;   // 0..127
    __shared__ int sE[KN], sR[KN], sT[KN];
    __shared__ float sAgg[3][DIM];
    __shared__ float sQ[DIM];
    __shared__ float sRed[DIM];

    if (t < KN) {
        sE[t] = ngh_node[b * KN + t];
        sR[t] = ngh_eidx[b * KN + t];
        sT[t] = ngh_ts[b * KN + t] - ts[b] + 364;
    }
    __syncthreads();

    float aN = 0.f, aC = 0.f, aR = 0.f;
    int cnt = 0;
    for (int k = 0; k < KN; ++k) {
        int e = sE[k];
        if (e < 0) continue;
        cnt++;
        aN += symbol_emb[e * DIM + t];
        aC += COS[sT[k] * DIM + t];
        aR += symbol_emb[(NUM_ENT + sR[k]) * DIM + t];
    }
    sAgg[0][t] = aN; sAgg[1][t] = aC; sAgg[2][t] = aR;
    __syncthreads();

    float acc = (float)cnt * bias[t];
    #pragma unroll 8
    for (int j = 0; j < DIM; ++j) acc += sAgg[0][j] * W[j * DIM + t];
    #pragma unroll 8
    for (int j = 0; j < DIM; ++j) acc += sAgg[1][j] * W[(128 + j) * DIM + t];
    #pragma unroll 8
    for (int j = 0; j < DIM; ++j) acc += sAgg[2][j] * W[(256 + j) * DIM + t];

    float denom = (float)(cnt > 0 ? cnt : 1);
    float sub = tanhf(acc / denom);
    float q = sub * symbol_emb[(NUM_ENT + rel_idx[b]) * DIM + t];
    sQ[t] = q;
    __syncthreads();

    float u = 0.f;
    #pragma unroll 8
    for (int dd = 0; dd < DIM; ++dd) u += sQ[dd] * proj_w[dd * 256 + t];
    uOut[b * DIM + t] = (_Float16)u;

    sRed[t] = q * Call[t];
    __syncthreads();
    for (int s = 64; s > 0; s >>= 1) {
        if (t < s) sRed[t] += sRed[t + s];
        __syncthreads();
    }
    if (t == 0) cOut[b] = sRed[0];
}

// ---------------- Kernel D: score^T fragments = Sf-tile (regs) x U ----------------
// Each block owns a 64-entity column tile (Sf frags pinned in VGPRs) and loops
// over 256 queries. mfma(a=Sf, b=U) -> D row=entity, col=query: each lane holds
// 4 consecutive entity scores for one query -> dwordx4 stores.
// Grid: 1D 3128 = 782 col-tiles x 4 query-chunks, XCD-chunked swizzle.
__global__ __launch_bounds__(256) void score_kernel(const _Float16* __restrict__ U,
                                                    const _Float16* __restrict__ Sf,
                                                    const float* __restrict__ cArr,
                                                    float* __restrict__ out) {
    // swizzle: 3128 = 8 XCDs * 391; within an XCD, 4 consecutive blocks share x
    int wgid = blockIdx.x;
    int swz = (wgid & 7) * 391 + (wgid >> 3);
    int xtile = swz >> 2;        // 0..781  (entity col-tile)
    int ychunk = swz & 3;        // 0..3    (query chunk of 256)

    int lane = threadIdx.x & 63;
    int wave = threadIdx.x >> 6;
    int n0 = xtile * 64;
    int lr = lane & 15;
    int lg = lane >> 4;          // 0..3
    int lk = lg * 8;             // k offset within 32

    // pin the 64x128 entity tile in registers: 16 x f16x8
    f16x8 a[4][4];
    #pragma unroll
    for (int nn = 0; nn < 4; ++nn)
        #pragma unroll
        for (int kk = 0; kk < 4; ++kk)
            a[nn][kk] = *reinterpret_cast<const f16x8*>(
                Sf + (size_t)(n0 + nn * 16 + lr) * DIM + kk * 32 + lk);

    int qblock = ychunk * 256;
    #pragma unroll
    for (int it = 0; it < 4; ++it) {
        int q0 = qblock + it * 64 + wave * 16;
        f16x8 bfr[4];
        #pragma unroll
        for (int kk = 0; kk < 4; ++kk)
            bfr[kk] = *reinterpret_cast<const f16x8*>(U + (q0 + lr) * DIM + kk * 32 + lk);
        float cv = cArr[q0 + lr];

        f32x4 acc[4];
        #pragma unroll
        for (int nn = 0; nn < 4; ++nn) acc[nn] = (f32x4){0.f, 0.f, 0.f, 0.f};

        #pragma unroll
        for (int kk = 0; kk < 4; ++kk)
            #pragma unroll
            for (int nn = 0; nn < 4; ++nn)
                acc[nn] = __builtin_amdgcn_mfma_f32_16x16x32_f16(a[nn][kk], bfr[kk], acc[nn], 0, 0, 0);

        int q = q0 + lr;
        #pragma unroll
        for (int nn = 0; nn < 4; ++nn) {
            int e = n0 + nn * 16 + lg * 4;
            if (e < NUM_ENT) {
                float4 v;
                v.x = acc[nn][0] + cv;
                v.y = acc[nn][1] + cv;
                v.z = acc[nn][2] + cv;
                v.w = acc[nn][3] + cv;
                *reinterpret_cast<float4*>(out + (size_t)q * NUM_ENT + e) = v;
            }
        }
    }
}

extern "C" void kernel_launch(void* const* d_in, const int* in_sizes, int n_in,
                              void* d_out, int out_size, void* d_ws, size_t ws_size,
                              hipStream_t stream) {
    const int*   rel_idx    = (const int*)d_in[1];
    const int*   ts         = (const int*)d_in[2];
    const int*   ngh_node   = (const int*)d_in[3];
    const int*   ngh_eidx   = (const int*)d_in[4];
    const int*   ngh_ts     = (const int*)d_in[5];
    const float* symbol_emb = (const float*)d_in[6];
    const float* gcn_w_w    = (const float*)d_in[7];
    const float* gcn_w_b    = (const float*)d_in[8];
    const float* proj_w     = (const float*)d_in[9];
    const float* proj_b     = (const float*)d_in[10];
    const float* basis_freq = (const float*)d_in[11];
    const float* phase      = (const float*)d_in[12];
    float* out = (float*)d_out;

    char* ws = (char*)d_ws;
    float*     W    = (float*)(ws + 0);          // 384*128*4 = 196608
    float*     bias = (float*)(ws + 196608);     // 512
    float*     Call = (float*)(ws + 197120);     // 512
    float*     COS  = (float*)(ws + 197632);     // 729*128*4 = 373248
    float*     cArr = (float*)(ws + 570880);     // 1024*4 = 4096
    _Float16*  U    = (_Float16*)(ws + 574976);  // 1024*128*2 = 262144
    _Float16*  Sf   = (_Float16*)(ws + 837120);  // 50048*128*2 = 12812288

    prep_weights<<<385, 128, 0, stream>>>(gcn_w_w, gcn_w_b, proj_w, proj_b, phase,
                                          W, bias, Call);
    prep_cos<<<(TBL * DIM + 255) / 256, 256, 0, stream>>>(basis_freq, phase, COS);
    conv_f16<<<NPAD * (DIM / 4) / 256, 256, 0, stream>>>(symbol_emb, Sf);
    query_kernel<<<BQ, 128, 0, stream>>>(rel_idx, ts, ngh_node, ngh_eidx, ngh_ts,
                                         symbol_emb, proj_w, W, bias, Call, COS,
                                         cArr, U);
    score_kernel<<<3128, 256, 0, stream>>>(U, Sf, cArr, out);
}

// Round 3
// 132.424 us; speedup vs baseline: 1.4632x; 1.0157x over previous
//
#include <hip/hip_runtime.h>
#include <hip/hip_bf16.h>

#define NUM_ENT 50000
#define NUM_REL 500
#define DIM 128
#define BQ 1024
#define KN 32
#define TBL 729          // dt in [-364, 364]
#define NPAD 50048       // 782*64

typedef _Float16 f16x8 __attribute__((ext_vector_type(8)));
typedef float f32x4 __attribute__((ext_vector_type(4)));

// ---------------- Kernel A: fold weights + cos table (fused) ----------------
// blocks 0..255:   W[j][d] = sum_f gcn_w_w[d,f] * proj_w[f,j]
// blocks 256..383: W[j][d] = gcn_w_w[d, 128 + (j-256)]
// block 384:       bias[d], Call[d]
// blocks 385..1113: COS rows (dt = blockIdx-385-364)
__global__ void prep_kernel(const float* __restrict__ gcn_w_w,
                            const float* __restrict__ gcn_w_b,
                            const float* __restrict__ proj_w,
                            const float* __restrict__ proj_b,
                            const float* __restrict__ phase,
                            const float* __restrict__ basis_freq,
                            float* __restrict__ W,
                            float* __restrict__ bias,
                            float* __restrict__ Call,
                            float* __restrict__ COS) {
    int j = blockIdx.x;
    int d = threadIdx.x;
    if (j < 256) {
        float acc = 0.f;
        for (int f = 0; f < DIM; ++f)
            acc += gcn_w_w[d * 256 + f] * proj_w[f * 256 + j];
        W[j * DIM + d] = acc;
    } else if (j < 384) {
        W[j * DIM + d] = gcn_w_w[d * 256 + 128 + (j - 256)];
    } else if (j == 384) {
        float b1 = 0.f;
        for (int f = 0; f < DIM; ++f) b1 += proj_b[f] * gcn_w_w[d * 256 + f];
        bias[d] = b1 + gcn_w_b[d];
        float cc = 0.f;
        for (int g = 0; g < DIM; ++g) cc += cosf(phase[g]) * proj_w[d * 256 + 128 + g];
        Call[d] = cc + proj_b[d];
    } else {
        int row = j - 385;                 // 0..728
        COS[row * DIM + d] = cosf((float)(row - 364) * basis_freq[d] + phase[d]);
    }
}

// ---------------- Kernel C: per-query pipeline (256 threads/query) ----------------
// Thread layout: d = t&127, h = t>>7. k-loop and j-dots split over h; partials in LDS.
__global__ __launch_bounds__(256) void query_kernel(const int* __restrict__ rel_idx,
                             const int* __restrict__ ts,
                             const int* __restrict__ ngh_node,
                             const int* __restrict__ ngh_eidx,
                             const int* __restrict__ ngh_ts,
                             const float* __restrict__ symbol_emb,
                             const float* __restrict__ proj_w,
                             const float* __restrict__ W,
                             const float* __restrict__ bias,
                             const float* __restrict__ Call,
                             const float* __restrict__ COS,
                             float* __restrict__ cOut,
                             _Float16* __restrict__ uOut) {
    int b = blockIdx.x;
    int t = threadIdx.x;          // 0..255
    int d = t & 127;
    int h = t >> 7;               // 0/1
    __shared__ int sE[KN], sR[KN], sT[KN];
    __shared__ float sAgg[2][3][DIM];
    __shared__ float sAcc[2][DIM];
    __shared__ float sQ[DIM];
    __shared__ float sU[2][DIM];
    __shared__ float sRed[DIM];

    if (t < KN) {
        sE[t] = ngh_node[b * KN + t];
        sR[t] = ngh_eidx[b * KN + t];
        sT[t] = ngh_ts[b * KN + t] - ts[b] + 364;
    }
    __syncthreads();

    // masked aggregation, k-range split by h
    float aN = 0.f, aC = 0.f, aR = 0.f;
    int k0 = h * 16;
    for (int k = k0; k < k0 + 16; ++k) {
        int e = sE[k];
        if (e < 0) continue;
        aN += symbol_emb[(size_t)e * DIM + d];
        aC += COS[sT[k] * DIM + d];
        aR += symbol_emb[(size_t)(NUM_ENT + sR[k]) * DIM + d];
    }
    sAgg[h][0][d] = aN; sAgg[h][1][d] = aC; sAgg[h][2][d] = aR;

    int cnt = 0;
    #pragma unroll
    for (int k = 0; k < KN; ++k) cnt += (sE[k] >= 0) ? 1 : 0;
    __syncthreads();

    // combine halves
    if (h == 0) {
        sAgg[0][0][d] += sAgg[1][0][d];
        sAgg[0][1][d] += sAgg[1][1][d];
        sAgg[0][2][d] += sAgg[1][2][d];
    }
    __syncthreads();

    // W dot, j-range split by h
    int j0 = h * 64;
    float acc = 0.f;
    #pragma unroll 8
    for (int j = 0; j < 64; ++j) acc += sAgg[0][0][j0 + j] * W[(j0 + j) * DIM + d];
    #pragma unroll 8
    for (int j = 0; j < 64; ++j) acc += sAgg[0][1][j0 + j] * W[(128 + j0 + j) * DIM + d];
    #pragma unroll 8
    for (int j = 0; j < 64; ++j) acc += sAgg[0][2][j0 + j] * W[(256 + j0 + j) * DIM + d];
    sAcc[h][d] = acc;
    __syncthreads();

    if (h == 0) {
        float total = sAcc[0][d] + sAcc[1][d] + (float)cnt * bias[d];
        float denom = (float)(cnt > 0 ? cnt : 1);
        float sub = tanhf(total / denom);
        float q = sub * symbol_emb[(size_t)(NUM_ENT + rel_idx[b]) * DIM + d];
        sQ[d] = q;
    }
    __syncthreads();

    // u = q @ P1, dd-range split by h
    float u = 0.f;
    #pragma unroll 8
    for (int dd = 0; dd < 64; ++dd) u += sQ[j0 + dd] * proj_w[(j0 + dd) * 256 + d];
    sU[h][d] = u;
    __syncthreads();
    if (h == 0) uOut[b * DIM + d] = (_Float16)(sU[0][d] + sU[1][d]);

    // c = q . Call
    if (h == 0) sRed[d] = sQ[d] * Call[d];
    __syncthreads();
    for (int s = 64; s > 0; s >>= 1) {
        if (t < s) sRed[t] += sRed[t + s];
        __syncthreads();
    }
    if (t == 0) cOut[b] = sRed[0];
}

// ---------------- Kernel D: score^T fragments = S-tile (f32->f16 regs) x U --------
// Each block owns a 64-entity column tile loaded straight from symbol_emb (f32,
// converted in registers) and loops over 256 queries. mfma(a=S, b=U) -> D
// row=entity, col=query: each lane holds 4 consecutive entity scores for one
// query -> dwordx4 stores. Grid: 3128 = 782 col-tiles x 4 q-chunks, XCD swizzle.
__global__ __launch_bounds__(256) void score_kernel(const _Float16* __restrict__ U,
                                                    const float* __restrict__ S,
                                                    const float* __restrict__ cArr,
                                                    float* __restrict__ out) {
    int wgid = blockIdx.x;
    int swz = (wgid & 7) * 391 + (wgid >> 3);   // 3128 = 8*391, bijective
    int xtile = swz >> 2;        // 0..781
    int ychunk = swz & 3;        // 0..3

    int lane = threadIdx.x & 63;
    int wave = threadIdx.x >> 6;
    int n0 = xtile * 64;
    int lr = lane & 15;
    int lg = lane >> 4;          // 0..3
    int lk = lg * 8;             // k offset within 32

    // 64x128 entity tile: load f32, convert to f16 fragments in registers.
    // Rows up to 50047 < 50501 total table rows -> always in-bounds; relation
    // rows that sneak into the last tile are never stored (e<NUM_ENT guard,
    // boundary 50000 is group-aligned).
    f16x8 a[4][4];
    #pragma unroll
    for (int nn = 0; nn < 4; ++nn) {
        const float* sp = S + (size_t)(n0 + nn * 16 + lr) * DIM + lk;
        #pragma unroll
        for (int kk = 0; kk < 4; ++kk) {
            float4 v0 = *reinterpret_cast<const float4*>(sp + kk * 32);
            float4 v1 = *reinterpret_cast<const float4*>(sp + kk * 32 + 4);
            f16x8 af;
            af[0] = (_Float16)v0.x; af[1] = (_Float16)v0.y;
            af[2] = (_Float16)v0.z; af[3] = (_Float16)v0.w;
            af[4] = (_Float16)v1.x; af[5] = (_Float16)v1.y;
            af[6] = (_Float16)v1.z; af[7] = (_Float16)v1.w;
            a[nn][kk] = af;
        }
    }

    int qblock = ychunk * 256;
    #pragma unroll
    for (int it = 0; it < 4; ++it) {
        int q0 = qblock + it * 64 + wave * 16;
        f16x8 bfr[4];
        #pragma unroll
        for (int kk = 0; kk < 4; ++kk)
            bfr[kk] = *reinterpret_cast<const f16x8*>(U + (q0 + lr) * DIM + kk * 32 + lk);
        float cv = cArr[q0 + lr];

        f32x4 acc[4];
        #pragma unroll
        for (int nn = 0; nn < 4; ++nn) acc[nn] = (f32x4){0.f, 0.f, 0.f, 0.f};

        #pragma unroll
        for (int kk = 0; kk < 4; ++kk)
            #pragma unroll
            for (int nn = 0; nn < 4; ++nn)
                acc[nn] = __builtin_amdgcn_mfma_f32_16x16x32_f16(a[nn][kk], bfr[kk], acc[nn], 0, 0, 0);

        int q = q0 + lr;
        #pragma unroll
        for (int nn = 0; nn < 4; ++nn) {
            int e = n0 + nn * 16 + lg * 4;
            if (e < NUM_ENT) {
                float4 v;
                v.x = acc[nn][0] + cv;
                v.y = acc[nn][1] + cv;
                v.z = acc[nn][2] + cv;
                v.w = acc[nn][3] + cv;
                *reinterpret_cast<float4*>(out + (size_t)q * NUM_ENT + e) = v;
            }
        }
    }
}

extern "C" void kernel_launch(void* const* d_in, const int* in_sizes, int n_in,
                              void* d_out, int out_size, void* d_ws, size_t ws_size,
                              hipStream_t stream) {
    const int*   rel_idx    = (const int*)d_in[1];
    const int*   ts         = (const int*)d_in[2];
    const int*   ngh_node   = (const int*)d_in[3];
    const int*   ngh_eidx   = (const int*)d_in[4];
    const int*   ngh_ts     = (const int*)d_in[5];
    const float* symbol_emb = (const float*)d_in[6];
    const float* gcn_w_w    = (const float*)d_in[7];
    const float* gcn_w_b    = (const float*)d_in[8];
    const float* proj_w     = (const float*)d_in[9];
    const float* proj_b     = (const float*)d_in[10];
    const float* basis_freq = (const float*)d_in[11];
    const float* phase      = (const float*)d_in[12];
    float* out = (float*)d_out;

    char* ws = (char*)d_ws;
    float*     W    = (float*)(ws + 0);          // 384*128*4 = 196608
    float*     bias = (float*)(ws + 196608);     // 512
    float*     Call = (float*)(ws + 197120);     // 512
    float*     COS  = (float*)(ws + 197632);     // 729*128*4 = 373248
    float*     cArr = (float*)(ws + 570880);     // 1024*4 = 4096
    _Float16*  U    = (_Float16*)(ws + 574976);  // 1024*128*2 = 262144

    prep_kernel<<<385 + TBL, 128, 0, stream>>>(gcn_w_w, gcn_w_b, proj_w, proj_b,
                                               phase, basis_freq, W, bias, Call, COS);
    query_kernel<<<BQ, 256, 0, stream>>>(rel_idx, ts, ngh_node, ngh_eidx, ngh_ts,
                                         symbol_emb, proj_w, W, bias, Call, COS,
                                         cArr, U);
    score_kernel<<<3128, 256, 0, stream>>>(U, symbol_emb, cArr, out);
}